// Round 1
// baseline (3287.424 us; speedup 1.0000x reference)
//
#include <hip/hip_runtime.h>
#include <cstddef>
#include <cstdint>

#define LRELU_SLOPE 0.2f

// m = x @ W (64x64), p = m·a1, q = m·a2   (one wave per row)
__global__ __launch_bounds__(256) void gemm_pq_kernel(
    const float* __restrict__ x, const float* __restrict__ W,
    const float* __restrict__ a, float* __restrict__ m,
    float* __restrict__ p, float* __restrict__ q, int n)
{
    const int lane = threadIdx.x & 63;
    // column `lane` of W held in registers
    float wreg[64];
#pragma unroll
    for (int k = 0; k < 64; ++k) wreg[k] = W[k * 64 + lane];
    const float a1 = a[lane];
    const float a2 = a[64 + lane];
    const int wstride = (gridDim.x * blockDim.x) >> 6;
    for (int i = (int)((blockIdx.x * blockDim.x + threadIdx.x) >> 6); i < n; i += wstride) {
        const int iu = __builtin_amdgcn_readfirstlane(i);   // wave-uniform -> scalar loads
        const float* __restrict__ xr = x + (size_t)iu * 64;
        float acc = 0.f;
#pragma unroll
        for (int k = 0; k < 64; ++k) acc = fmaf(xr[k], wreg[k], acc);
        m[(size_t)iu * 64 + lane] = acc;
        float t1 = acc * a1;
        float t2 = acc * a2;
#pragma unroll
        for (int off = 1; off < 64; off <<= 1) {
            t1 += __shfl_xor(t1, off);
            t2 += __shfl_xor(t2, off);
        }
        if (lane == 0) { p[iu] = t1; q[iu] = t2; }
    }
}

// single-direction logits: ex = exp(lrelu(pA[ia]+pB[ib])), s[iseg] += ex
__global__ __launch_bounds__(256) void edge_logits(
    const int* __restrict__ ia, const int* __restrict__ ib, const int* __restrict__ iseg,
    const float* __restrict__ pA, const float* __restrict__ pB,
    float* __restrict__ ex, float* __restrict__ s, int E)
{
    int k = blockIdx.x * blockDim.x + threadIdx.x;
    if (k >= E) return;
    float v = pA[ia[k]] + pB[ib[k]];
    v = (v > 0.f) ? v : LRELU_SLOPE * v;
    float e = __expf(v);
    ex[k] = e;
    unsafeAtomicAdd(&s[iseg[k]], e);
}

// both HBNS directions fused (layer 1)
__global__ __launch_bounds__(256) void edge_logits_bi(
    const int* __restrict__ ti, const int* __restrict__ sj,
    const float* __restrict__ ps, const float* __restrict__ qs,
    const float* __restrict__ pt, const float* __restrict__ qt,
    float* __restrict__ exE, float* __restrict__ exF,
    float* __restrict__ sE, float* __restrict__ sF, int E)
{
    int k = blockIdx.x * blockDim.x + threadIdx.x;
    if (k >= E) return;
    int i = ti[k], j = sj[k];
    float e = ps[j] + qt[i];
    e = (e > 0.f) ? e : LRELU_SLOPE * e;
    e = __expf(e);
    float f = pt[i] + qs[j];
    f = (f > 0.f) ? f : LRELU_SLOPE * f;
    f = __expf(f);
    exE[k] = e;
    exF[k] = f;
    unsafeAtomicAdd(&sE[i], e);
    unsafeAtomicAdd(&sF[j], f);
}

// one wave per edge: out[seg] += (ex/s[seg]) * feat[gather]
__global__ __launch_bounds__(256) void edge_scatter(
    const int* __restrict__ iseg, const int* __restrict__ ig,
    const float* __restrict__ ex, const float* __restrict__ s,
    const float* __restrict__ feat, float* __restrict__ out, int E)
{
    const int lane = threadIdx.x & 63;
    int e = (int)((blockIdx.x * blockDim.x + threadIdx.x) >> 6);
    if (e >= E) return;
    const int si = iseg[e];
    const int gi = ig[e];
    const float wgt = ex[e] / s[si];
    const float v = wgt * feat[(size_t)gi * 64 + lane];
    unsafeAtomicAdd(&out[(size_t)si * 64 + lane], v);
}

extern "C" void kernel_launch(void* const* d_in, const int* in_sizes, int n_in,
                              void* d_out, int out_size, void* d_ws, size_t ws_size,
                              hipStream_t stream)
{
    const float* x0 = (const float*)d_in[0];
    const float* x1 = (const float*)d_in[1];
    const float* x2 = (const float*)d_in[2];
    const float* x3 = (const float*)d_in[3];
    const float* hbsW = (const float*)d_in[4];  // [5][64][64]
    const float* hbsA = (const float*)d_in[5];  // [5][128]
    const float* hWs  = (const float*)d_in[6];  // [6][64][64]
    const float* hWt  = (const float*)d_in[7];  // [6][64][64]
    const float* hA   = (const float*)d_in[8];  // [6][128]
    const int* a0r = (const int*)d_in[9];  const int* a0c = (const int*)d_in[10];
    const int* a1r = (const int*)d_in[11]; const int* a1c = (const int*)d_in[12];
    const int* a2r = (const int*)d_in[13]; const int* a2c = (const int*)d_in[14];
    const int* c3r = (const int*)d_in[15]; const int* c3c = (const int*)d_in[16];
    const int* i1r = (const int*)d_in[17]; const int* i1c = (const int*)d_in[18];
    const int* i2r = (const int*)d_in[19]; const int* i2c = (const int*)d_in[20];
    const int* i3r = (const int*)d_in[21]; const int* i3c = (const int*)d_in[22];

    const int n0 = in_sizes[0] / 64, n1 = in_sizes[1] / 64;
    const int n2 = in_sizes[2] / 64, n3 = in_sizes[3] / 64;
    const int Ea0 = in_sizes[9],  Ea1 = in_sizes[11], Ea2 = in_sizes[13], Ec3 = in_sizes[15];
    const int Ei1 = in_sizes[17], Ei2 = in_sizes[19], Ei3 = in_sizes[21];

    int nm = n0; if (n1 > nm) nm = n1; if (n2 > nm) nm = n2; if (n3 > nm) nm = n3;
    int Em = Ea0; if (Ea1 > Em) Em = Ea1; if (Ea2 > Em) Em = Ea2; if (Ec3 > Em) Em = Ec3;
    if (Ei1 > Em) Em = Ei1; if (Ei2 > Em) Em = Ei2; if (Ei3 > Em) Em = Ei3;
    int Efm = Ei1; if (Ei2 > Efm) Efm = Ei2; if (Ei3 > Efm) Efm = Ei3;

    float* w = (float*)d_ws;
    size_t off = 0;
    auto alloc = [&](size_t nel) { float* r = w + off; off += nel; return r; };
    float* featA = alloc((size_t)nm * 64);
    float* featB = alloc((size_t)nm * 64);
    float* xl10  = alloc((size_t)n0 * 64);   // layer-1 activations (contiguous for one memset)
    float* xl11  = alloc((size_t)n1 * 64);
    float* xl12  = alloc((size_t)n2 * 64);
    float* xl13  = alloc((size_t)n3 * 64);
    float* pA = alloc(nm); float* qA = alloc(nm);
    float* pB = alloc(nm); float* qB = alloc(nm);
    float* exE = alloc((size_t)Em);
    float* exF = alloc((size_t)Efm);
    float* sbase = w + off;                  // softmax denominators (contiguous, one memset)
    float* sA0L1 = alloc(n0);
    float* sI1e = alloc(n0); float* sI1f = alloc(n1);
    float* sI2e = alloc(n1); float* sI2f = alloc(n2);
    float* sI3e = alloc(n2); float* sI3f = alloc(n3);
    float* sA0 = alloc(n0); float* sA1 = alloc(n1); float* sA2 = alloc(n2); float* sC3 = alloc(n3);
    float* sF1 = alloc(n1); float* sF2 = alloc(n2); float* sF3 = alloc(n3);
    size_t scount = (size_t)((w + off) - sbase);

    if (off * sizeof(float) > ws_size) {
        // workspace too small: fail cleanly (diagnostic: absmax == max|ref|)
        hipMemsetAsync(d_out, 0, (size_t)out_size * sizeof(float), stream);
        return;
    }

    float* out  = (float*)d_out;
    float* out0 = out;
    float* out1 = out0 + (size_t)n0 * 64;
    float* out2 = out1 + (size_t)n1 * 64;
    float* out3 = out2 + (size_t)n2 * 64;

    hipMemsetAsync(xl10, 0, (size_t)(n0 + n1 + n2 + n3) * 64 * sizeof(float), stream);
    hipMemsetAsync(sbase, 0, scount * sizeof(float), stream);
    hipMemsetAsync(d_out, 0, (size_t)out_size * sizeof(float), stream);

    auto gemm = [&](const float* xx, const float* WW, const float* aa,
                    float* mm, float* pp, float* qq, int n) {
        int grid = (n + 3) / 4; if (grid > 4096) grid = 4096;
        gemm_pq_kernel<<<dim3(grid), dim3(256), 0, stream>>>(xx, WW, aa, mm, pp, qq, n);
    };
    auto logits = [&](const int* ia, const int* ib, const int* iseg,
                      const float* ppA, const float* ppB, float* ex, float* s, int E) {
        edge_logits<<<dim3((E + 255) / 256), dim3(256), 0, stream>>>(ia, ib, iseg, ppA, ppB, ex, s, E);
    };
    auto logits_bi = [&](const int* ti, const int* sj,
                         const float* ps, const float* qs, const float* pt, const float* qt,
                         float* eE, float* eF, float* sE, float* sF, int E) {
        edge_logits_bi<<<dim3((E + 255) / 256), dim3(256), 0, stream>>>(ti, sj, ps, qs, pt, qt, eE, eF, sE, sF, E);
    };
    auto scat = [&](const int* iseg, const int* ig, const float* ex, const float* s,
                    const float* feat, float* outp, int E) {
        edge_scatter<<<dim3((E + 3) / 4), dim3(256), 0, stream>>>(iseg, ig, ex, s, feat, outp, E);
    };

    // ---------------- Layer 1 ----------------
    // x00 = hbs(x_0, adj0, W[0], a[0]) -> xl10
    gemm(x0, hbsW + 0 * 4096, hbsA + 0 * 128, featA, pA, qA, n0);
    logits(a0r, a0c, a0r, pA, qA, exE, sA0L1, Ea0);
    scat(a0r, a0c, exE, sA0L1, featA, xl10, Ea0);

    // x01, x10 = hbns(x_1, x_0, inc1)  [Ws0, Wt0, a0]
    gemm(x1, hWs + 0 * 4096, hA + 0 * 128, featA, pA, qA, n1);   // sm: ps=pA, qs=qA
    gemm(x0, hWt + 0 * 4096, hA + 0 * 128, featB, pB, qB, n0);   // tm: pt=pB, qt=qB
    logits_bi(i1r, i1c, pA, qA, pB, qB, exE, exF, sI1e, sI1f, Ei1);
    scat(i1r, i1c, exE, sI1e, featA, xl10, Ei1);                 // msg_t (x10) -> xl10
    scat(i1c, i1r, exF, sI1f, featB, xl11, Ei1);                 // msg_s (x01) -> xl11

    // x12, x21 = hbns(x_2, x_1, inc2)  [Ws1, Wt1, a1]
    gemm(x2, hWs + 1 * 4096, hA + 1 * 128, featA, pA, qA, n2);
    gemm(x1, hWt + 1 * 4096, hA + 1 * 128, featB, pB, qB, n1);
    logits_bi(i2r, i2c, pA, qA, pB, qB, exE, exF, sI2e, sI2f, Ei2);
    scat(i2r, i2c, exE, sI2e, featA, xl11, Ei2);                 // msg_t (x21) -> xl11
    scat(i2c, i2r, exF, sI2f, featB, xl12, Ei2);                 // msg_s (x12) -> xl12

    // x23, x32 = hbns(x_3, x_2, inc3)  [Ws2, Wt2, a2]
    gemm(x3, hWs + 2 * 4096, hA + 2 * 128, featA, pA, qA, n3);
    gemm(x2, hWt + 2 * 4096, hA + 2 * 128, featB, pB, qB, n2);
    logits_bi(i3r, i3c, pA, qA, pB, qB, exE, exF, sI3e, sI3f, Ei3);
    scat(i3r, i3c, exE, sI3e, featA, xl12, Ei3);                 // msg_t (x32) -> xl12
    scat(i3c, i3r, exF, sI3f, featB, xl13, Ei3);                 // msg_s (x23) -> xl13

    // ---------------- Layer 2 ----------------
    // y00 = hbs(xl10, adj0, W[1], a[1]) -> out0
    gemm(xl10, hbsW + 1 * 4096, hbsA + 1 * 128, featA, pA, qA, n0);
    logits(a0r, a0c, a0r, pA, qA, exE, sA0, Ea0);
    scat(a0r, a0c, exE, sA0, featA, out0, Ea0);

    // y11 = hbs(xl11, adj1, W[2], a[2]) -> out1
    gemm(xl11, hbsW + 2 * 4096, hbsA + 2 * 128, featA, pA, qA, n1);
    logits(a1r, a1c, a1r, pA, qA, exE, sA1, Ea1);
    scat(a1r, a1c, exE, sA1, featA, out1, Ea1);

    // y22 = hbs(xl12, adj2, W[3], a[3]) -> out2
    gemm(xl12, hbsW + 3 * 4096, hbsA + 3 * 128, featA, pA, qA, n2);
    logits(a2r, a2c, a2r, pA, qA, exE, sA2, Ea2);
    scat(a2r, a2c, exE, sA2, featA, out2, Ea2);

    // y33 = hbs(xl13, coadj3, W[4], a[4]) -> out3
    gemm(xl13, hbsW + 4 * 4096, hbsA + 4 * 128, featA, pA, qA, n3);
    logits(c3r, c3c, c3r, pA, qA, exE, sC3, Ec3);
    scat(c3r, c3c, exE, sC3, featA, out3, Ec3);

    // y01 = msg_s of hbns(xl11, xl10, inc1) [Ws3, Wt3, a3] -> out1
    gemm(xl11, hWs + 3 * 4096, hA + 3 * 128, featA, pA, qA, n1);  // sm: qA = q_s
    gemm(xl10, hWt + 3 * 4096, hA + 3 * 128, featB, pB, qB, n0);  // tm: pB = p_t
    logits(i1r, i1c, i1c, pB, qA, exE, sF1, Ei1);                 // f = lrelu(p_t[ti]+q_s[sj]), seg=sj
    scat(i1c, i1r, exE, sF1, featB, out1, Ei1);                   // out1 += att_f * tm[ti]

    // y12 = msg_s of hbns(xl12, xl11, inc2) [Ws4, Wt4, a4] -> out2
    gemm(xl12, hWs + 4 * 4096, hA + 4 * 128, featA, pA, qA, n2);
    gemm(xl11, hWt + 4 * 4096, hA + 4 * 128, featB, pB, qB, n1);
    logits(i2r, i2c, i2c, pB, qA, exE, sF2, Ei2);
    scat(i2c, i2r, exE, sF2, featB, out2, Ei2);

    // y23 = msg_s of hbns(xl13, xl12, inc3) [Ws5, Wt5, a5] -> out3
    gemm(xl13, hWs + 5 * 4096, hA + 5 * 128, featA, pA, qA, n3);
    gemm(xl12, hWt + 5 * 4096, hA + 5 * 128, featB, pB, qB, n2);
    logits(i3r, i3c, i3c, pB, qA, exE, sF3, Ei3);
    scat(i3c, i3r, exE, sF3, featB, out3, Ei3);
}

// Round 2
// 2975.297 us; speedup vs baseline: 1.1049x; 1.1049x over previous
//
#include <hip/hip_runtime.h>
#include <cstddef>
#include <cstdint>

#define LRELU_SLOPE 0.2f
#define SCAN_BLK 256
#define SCAN_ELEMS 2048   // 8 per thread

// m = x @ W (64x64), p = m·a1, q = m·a2   (one wave per row)
__global__ __launch_bounds__(256) void gemm_pq_kernel(
    const float* __restrict__ x, const float* __restrict__ W,
    const float* __restrict__ a, float* __restrict__ m,
    float* __restrict__ p, float* __restrict__ q, int n)
{
    const int lane = threadIdx.x & 63;
    float wreg[64];
#pragma unroll
    for (int k = 0; k < 64; ++k) wreg[k] = W[k * 64 + lane];
    const float a1 = a[lane];
    const float a2 = a[64 + lane];
    const int wstride = (gridDim.x * blockDim.x) >> 6;
    for (int i = (int)((blockIdx.x * blockDim.x + threadIdx.x) >> 6); i < n; i += wstride) {
        const int iu = __builtin_amdgcn_readfirstlane(i);   // wave-uniform -> scalar loads
        const float* __restrict__ xr = x + (size_t)iu * 64;
        float acc = 0.f;
#pragma unroll
        for (int k = 0; k < 64; ++k) acc = fmaf(xr[k], wreg[k], acc);
        m[(size_t)iu * 64 + lane] = acc;
        float t1 = acc * a1;
        float t2 = acc * a2;
#pragma unroll
        for (int off = 1; off < 64; off <<= 1) {
            t1 += __shfl_xor(t1, off);
            t2 += __shfl_xor(t2, off);
        }
        if (lane == 0) { p[iu] = t1; q[iu] = t2; }
    }
}

// ---------------- CSR build ----------------
__global__ __launch_bounds__(256) void hist1(const int* __restrict__ seg,
                                             int* __restrict__ counts, int base, int E)
{
    int k = blockIdx.x * blockDim.x + threadIdx.x;
    if (k < E) atomicAdd(&counts[base + seg[k]], 1);
}

__global__ __launch_bounds__(256) void hist2(const int* __restrict__ a, const int* __restrict__ b,
                                             int* __restrict__ counts, int baseA, int baseB, int E)
{
    int k = blockIdx.x * blockDim.x + threadIdx.x;
    if (k < E) {
        atomicAdd(&counts[baseA + a[k]], 1);
        atomicAdd(&counts[baseB + b[k]], 1);
    }
}

__global__ __launch_bounds__(SCAN_BLK) void scan_partial(const int* __restrict__ in,
                                                         int* __restrict__ out,
                                                         int* __restrict__ bsums, int n)
{
    __shared__ int lds[SCAN_BLK];
    int base = blockIdx.x * SCAN_ELEMS + threadIdx.x * 8;
    int v[8]; int s = 0;
#pragma unroll
    for (int k = 0; k < 8; ++k) { int x = (base + k < n) ? in[base + k] : 0; v[k] = s; s += x; }
    lds[threadIdx.x] = s;
    __syncthreads();
    int t = s;
    for (int off = 1; off < SCAN_BLK; off <<= 1) {
        int y = (threadIdx.x >= off) ? lds[threadIdx.x - off] : 0;
        __syncthreads();
        t += y;
        lds[threadIdx.x] = t;
        __syncthreads();
    }
    int excl = t - s;
    if (threadIdx.x == SCAN_BLK - 1) bsums[blockIdx.x] = t;
#pragma unroll
    for (int k = 0; k < 8; ++k) if (base + k < n) out[base + k] = excl + v[k];
}

__global__ __launch_bounds__(1024) void scan_top(int* __restrict__ bsums, int nb)
{
    __shared__ int lds[1024];
    int x = (threadIdx.x < nb) ? bsums[threadIdx.x] : 0;
    lds[threadIdx.x] = x;
    __syncthreads();
    int t = x;
    for (int off = 1; off < 1024; off <<= 1) {
        int y = (threadIdx.x >= off) ? lds[threadIdx.x - off] : 0;
        __syncthreads();
        t += y;
        lds[threadIdx.x] = t;
        __syncthreads();
    }
    if (threadIdx.x < nb) bsums[threadIdx.x] = t - x;
}

__global__ __launch_bounds__(256) void scan_addback(int* __restrict__ out,
                                                    const int* __restrict__ bsums, int n)
{
    int i = blockIdx.x * blockDim.x + threadIdx.x;
    if (i < n) out[i] += bsums[i / SCAN_ELEMS];
}

// reverse-fill buckets using counts as countdown cursors
__global__ __launch_bounds__(256) void place1(const int* __restrict__ seg, const int* __restrict__ other,
                                              const int* __restrict__ rs, int* __restrict__ counts,
                                              int* __restrict__ colsAll, int base, int E)
{
    int k = blockIdx.x * blockDim.x + threadIdx.x;
    if (k >= E) return;
    int s = base + seg[k];
    int off = atomicSub(&counts[s], 1) - 1;
    colsAll[rs[s] + off] = other[k];
}

__global__ __launch_bounds__(256) void place2(const int* __restrict__ a, const int* __restrict__ b,
                                              const int* __restrict__ rs, int* __restrict__ counts,
                                              int* __restrict__ colsAll, int baseA, int baseB, int E)
{
    int k = blockIdx.x * blockDim.x + threadIdx.x;
    if (k >= E) return;
    int av = a[k], bv = b[k];
    int sa = baseA + av;
    int offa = atomicSub(&counts[sa], 1) - 1;
    colsAll[rs[sa] + offa] = bv;
    int sb = baseB + bv;
    int offb = atomicSub(&counts[sb], 1) - 1;
    colsAll[rs[sb] + offb] = av;
}

// ---------------- segment aggregation (one wave per row) ----------------
// out[row] += sum_e exp(lrelu(uni[row]+gat[col_e])) * feat[col_e]  / sum_e exp(...)
__global__ __launch_bounds__(256) void seg_agg(
    const int* __restrict__ rs, const int* __restrict__ cols,
    const float* __restrict__ uni, const float* __restrict__ gat,
    const float* __restrict__ feat, float* __restrict__ out, int n)
{
    const int lane = threadIdx.x & 63;
    int row = (int)((blockIdx.x * blockDim.x + threadIdx.x) >> 6);
    if (row >= n) return;
    int e0 = rs[row], e1 = rs[row + 1];
    if (e0 >= e1) return;             // empty row: leave zeros (avoid 0/0)
    const float pu = uni[row];
    float acc = 0.f, ssum = 0.f;
    for (int j0 = e0; j0 < e1; j0 += 64) {
        int jj = j0 + lane;
        bool valid = jj < e1;
        int c = valid ? cols[jj] : 0;
        float w = 0.f;
        if (valid) {
            float t = pu + gat[c];
            t = (t > 0.f) ? t : LRELU_SLOPE * t;
            w = __expf(t);
        }
        ssum += w;
        int cnt = e1 - j0; if (cnt > 64) cnt = 64;
        for (int t = 0; t < cnt; ++t) {
            int   ct = __shfl(c, t);
            float wt = __shfl(w, t);
            acc = fmaf(wt, feat[(size_t)ct * 64 + lane], acc);
        }
    }
#pragma unroll
    for (int off = 1; off < 64; off <<= 1) ssum += __shfl_xor(ssum, off);
    out[(size_t)row * 64 + lane] += acc / ssum;
}

extern "C" void kernel_launch(void* const* d_in, const int* in_sizes, int n_in,
                              void* d_out, int out_size, void* d_ws, size_t ws_size,
                              hipStream_t stream)
{
    const float* x0 = (const float*)d_in[0];
    const float* x1 = (const float*)d_in[1];
    const float* x2 = (const float*)d_in[2];
    const float* x3 = (const float*)d_in[3];
    const float* hbsW = (const float*)d_in[4];
    const float* hbsA = (const float*)d_in[5];
    const float* hWs  = (const float*)d_in[6];
    const float* hWt  = (const float*)d_in[7];
    const float* hA   = (const float*)d_in[8];
    const int* a0r = (const int*)d_in[9];  const int* a0c = (const int*)d_in[10];
    const int* a1r = (const int*)d_in[11]; const int* a1c = (const int*)d_in[12];
    const int* a2r = (const int*)d_in[13]; const int* a2c = (const int*)d_in[14];
    const int* c3r = (const int*)d_in[15]; const int* c3c = (const int*)d_in[16];
    const int* i1r = (const int*)d_in[17]; const int* i1c = (const int*)d_in[18];
    const int* i2r = (const int*)d_in[19]; const int* i2c = (const int*)d_in[20];
    const int* i3r = (const int*)d_in[21]; const int* i3c = (const int*)d_in[22];

    const int n0 = in_sizes[0] / 64, n1 = in_sizes[1] / 64;
    const int n2 = in_sizes[2] / 64, n3 = in_sizes[3] / 64;
    const int Ea0 = in_sizes[9],  Ea1 = in_sizes[11], Ea2 = in_sizes[13], Ec3 = in_sizes[15];
    const int Ei1 = in_sizes[17], Ei2 = in_sizes[19], Ei3 = in_sizes[21];

    int nm = n0; if (n1 > nm) nm = n1; if (n2 > nm) nm = n2; if (n3 > nm) nm = n3;

    // CSR bases (concatenated rows): adj0,adj1,adj2,c3, i1t(n0), i1s(n1), i2t(n1), i2s(n2), i3t(n2), i3s(n3)
    int b_adj0 = 0;
    int b_adj1 = b_adj0 + n0;
    int b_adj2 = b_adj1 + n1;
    int b_c3   = b_adj2 + n2;
    int b_i1t  = b_c3   + n3;
    int b_i1s  = b_i1t  + n0;
    int b_i2t  = b_i1s  + n1;
    int b_i2s  = b_i2t  + n1;
    int b_i3t  = b_i2s  + n2;
    int b_i3s  = b_i3t  + n2;
    int NC     = b_i3s  + n3 + 1;   // +1 sentinel (count 0 -> scan value = total edges)
    // edge bases into colsAll
    long long eTot = (long long)Ea0 + Ea1 + Ea2 + Ec3 + 2LL * (Ei1 + Ei2 + Ei3);

    float* w = (float*)d_ws;
    size_t off = 0;
    auto allocf = [&](size_t nel) { float* r = w + off; off += nel; return r; };
    float* featA = allocf((size_t)nm * 64);
    float* featB = allocf((size_t)nm * 64);
    float* xl10  = allocf((size_t)n0 * 64);   // layer-1 activations (contiguous, one memset)
    float* xl11  = allocf((size_t)n1 * 64);
    float* xl12  = allocf((size_t)n2 * 64);
    float* xl13  = allocf((size_t)n3 * 64);
    float* pA = allocf(nm); float* qA = allocf(nm);
    float* pB = allocf(nm); float* qB = allocf(nm);
    int* counts  = (int*)allocf((size_t)NC);
    int* rs      = (int*)allocf((size_t)NC);
    int* bsums   = (int*)allocf(1024);
    int* colsAll = (int*)allocf((size_t)eTot);

    if (off * sizeof(float) > ws_size) {
        hipMemsetAsync(d_out, 0, (size_t)out_size * sizeof(float), stream);
        return;
    }

    float* out  = (float*)d_out;
    float* out0 = out;
    float* out1 = out0 + (size_t)n0 * 64;
    float* out2 = out1 + (size_t)n1 * 64;
    float* out3 = out2 + (size_t)n2 * 64;

    hipMemsetAsync(xl10, 0, (size_t)(n0 + n1 + n2 + n3) * 64 * sizeof(float), stream);
    hipMemsetAsync(counts, 0, (size_t)NC * sizeof(int), stream);
    hipMemsetAsync(d_out, 0, (size_t)out_size * sizeof(float), stream);

    auto blks = [](int n, int per) { return dim3((unsigned)((n + per - 1) / per)); };

    // ---- CSR build ----
    hist1<<<blks(Ea0, 256), 256, 0, stream>>>(a0r, counts, b_adj0, Ea0);
    hist1<<<blks(Ea1, 256), 256, 0, stream>>>(a1r, counts, b_adj1, Ea1);
    hist1<<<blks(Ea2, 256), 256, 0, stream>>>(a2r, counts, b_adj2, Ea2);
    hist1<<<blks(Ec3, 256), 256, 0, stream>>>(c3r, counts, b_c3,  Ec3);
    hist2<<<blks(Ei1, 256), 256, 0, stream>>>(i1r, i1c, counts, b_i1t, b_i1s, Ei1);
    hist2<<<blks(Ei2, 256), 256, 0, stream>>>(i2r, i2c, counts, b_i2t, b_i2s, Ei2);
    hist2<<<blks(Ei3, 256), 256, 0, stream>>>(i3r, i3c, counts, b_i3t, b_i3s, Ei3);

    int nb = (NC + SCAN_ELEMS - 1) / SCAN_ELEMS;   // ~660 <= 1024
    scan_partial<<<dim3((unsigned)nb), SCAN_BLK, 0, stream>>>(counts, rs, bsums, NC);
    scan_top<<<dim3(1), 1024, 0, stream>>>(bsums, nb);
    scan_addback<<<blks(NC, 256), 256, 0, stream>>>(rs, bsums, NC);

    place1<<<blks(Ea0, 256), 256, 0, stream>>>(a0r, a0c, rs, counts, colsAll, b_adj0, Ea0);
    place1<<<blks(Ea1, 256), 256, 0, stream>>>(a1r, a1c, rs, counts, colsAll, b_adj1, Ea1);
    place1<<<blks(Ea2, 256), 256, 0, stream>>>(a2r, a2c, rs, counts, colsAll, b_adj2, Ea2);
    place1<<<blks(Ec3, 256), 256, 0, stream>>>(c3r, c3c, rs, counts, colsAll, b_c3,  Ec3);
    place2<<<blks(Ei1, 256), 256, 0, stream>>>(i1r, i1c, rs, counts, colsAll, b_i1t, b_i1s, Ei1);
    place2<<<blks(Ei2, 256), 256, 0, stream>>>(i2r, i2c, rs, counts, colsAll, b_i2t, b_i2s, Ei2);
    place2<<<blks(Ei3, 256), 256, 0, stream>>>(i3r, i3c, rs, counts, colsAll, b_i3t, b_i3s, Ei3);

    auto gemm = [&](const float* xx, const float* WW, const float* aa,
                    float* mm, float* pp, float* qq, int n) {
        gemm_pq_kernel<<<blks(n, 4), 256, 0, stream>>>(xx, WW, aa, mm, pp, qq, n);
    };
    auto agg = [&](int base, const float* uni, const float* gat,
                   const float* feat, float* outp, int n) {
        seg_agg<<<blks(n, 4), 256, 0, stream>>>(rs + base, colsAll, uni, gat, feat, outp, n);
    };

    // ---------------- Layer 1 ----------------
    // x00 = hbs(x_0, adj0, W0, a0): e = lrelu(p[row]+q[col])
    gemm(x0, hbsW + 0 * 4096, hbsA + 0 * 128, featA, pA, qA, n0);
    agg(b_adj0, pA, qA, featA, xl10, n0);

    // x01, x10 = hbns(x_1, x_0, inc1) [Ws0, Wt0, a0]
    gemm(x1, hWs + 0 * 4096, hA + 0 * 128, featA, pA, qA, n1);   // sm: pA=sm·a1, qA=sm·a2
    gemm(x0, hWt + 0 * 4096, hA + 0 * 128, featB, pB, qB, n0);   // tm: pB=tm·a1, qB=tm·a2
    agg(b_i1t, qB, pA, featA, xl10, n0);   // e = lrelu(sm_j·a1 + tm_i·a2): uni=qB(row), gat=pA(col)
    agg(b_i1s, qA, pB, featB, xl11, n1);   // f = lrelu(tm_i·a1 + sm_j·a2): uni=qA(row), gat=pB(col)

    // x12, x21 = hbns(x_2, x_1, inc2) [Ws1, Wt1, a1]
    gemm(x2, hWs + 1 * 4096, hA + 1 * 128, featA, pA, qA, n2);
    gemm(x1, hWt + 1 * 4096, hA + 1 * 128, featB, pB, qB, n1);
    agg(b_i2t, qB, pA, featA, xl11, n1);   // x21 (msg_t)
    agg(b_i2s, qA, pB, featB, xl12, n2);   // x12 (msg_s)

    // x23, x32 = hbns(x_3, x_2, inc3) [Ws2, Wt2, a2]
    gemm(x3, hWs + 2 * 4096, hA + 2 * 128, featA, pA, qA, n3);
    gemm(x2, hWt + 2 * 4096, hA + 2 * 128, featB, pB, qB, n2);
    agg(b_i3t, qB, pA, featA, xl12, n2);   // x32
    agg(b_i3s, qA, pB, featB, xl13, n3);   // x23

    // ---------------- Layer 2 ----------------
    gemm(xl10, hbsW + 1 * 4096, hbsA + 1 * 128, featA, pA, qA, n0);
    agg(b_adj0, pA, qA, featA, out0, n0);                          // y00

    gemm(xl11, hbsW + 2 * 4096, hbsA + 2 * 128, featA, pA, qA, n1);
    agg(b_adj1, pA, qA, featA, out1, n1);                          // y11

    gemm(xl12, hbsW + 3 * 4096, hbsA + 3 * 128, featA, pA, qA, n2);
    agg(b_adj2, pA, qA, featA, out2, n2);                          // y22

    gemm(xl13, hbsW + 4 * 4096, hbsA + 4 * 128, featA, pA, qA, n3);
    agg(b_c3, pA, qA, featA, out3, n3);                            // y33

    // y01 = msg_s of hbns(xl11, xl10, inc1) [Ws3, Wt3, a3]
    gemm(xl11, hWs + 3 * 4096, hA + 3 * 128, featA, pA, qA, n1);
    gemm(xl10, hWt + 3 * 4096, hA + 3 * 128, featB, pB, qB, n0);
    agg(b_i1s, qA, pB, featB, out1, n1);

    // y12 = msg_s of hbns(xl12, xl11, inc2) [Ws4, Wt4, a4]
    gemm(xl12, hWs + 4 * 4096, hA + 4 * 128, featA, pA, qA, n2);
    gemm(xl11, hWt + 4 * 4096, hA + 4 * 128, featB, pB, qB, n1);
    agg(b_i2s, qA, pB, featB, out2, n2);

    // y23 = msg_s of hbns(xl13, xl12, inc3) [Ws5, Wt5, a5]
    gemm(xl13, hWs + 5 * 4096, hA + 5 * 128, featA, pA, qA, n3);
    gemm(xl12, hWs ? hWt + 5 * 4096 : nullptr, hA + 5 * 128, featB, pB, qB, n2);
    agg(b_i3s, qA, pB, featB, out3, n3);
}

// Round 3
// 2444.336 us; speedup vs baseline: 1.3449x; 1.2172x over previous
//
#include <hip/hip_runtime.h>
#include <cstddef>
#include <cstdint>

#define LRELU_SLOPE 0.2f
#define SCAN_BLK 256
#define SCAN_ELEMS 2048   // 8 per thread

// m = x @ W (64x64), p = m·a1, q = m·a2   (one wave per row)
__global__ __launch_bounds__(256) void gemm_pq_kernel(
    const float* __restrict__ x, const float* __restrict__ W,
    const float* __restrict__ a, float* __restrict__ m,
    float* __restrict__ p, float* __restrict__ q, int n)
{
    const int lane = threadIdx.x & 63;
    float wreg[64];
#pragma unroll
    for (int k = 0; k < 64; ++k) wreg[k] = W[k * 64 + lane];
    const float a1 = a[lane];
    const float a2 = a[64 + lane];
    const int wstride = (gridDim.x * blockDim.x) >> 6;
    for (int i = (int)((blockIdx.x * blockDim.x + threadIdx.x) >> 6); i < n; i += wstride) {
        const int iu = __builtin_amdgcn_readfirstlane(i);   // wave-uniform -> scalar loads
        const float* __restrict__ xr = x + (size_t)iu * 64;
        // 4 independent accumulators: dep chain 256 -> 64 cycles
        float acc0 = 0.f, acc1 = 0.f, acc2 = 0.f, acc3 = 0.f;
#pragma unroll
        for (int k = 0; k < 64; k += 4) {
            acc0 = fmaf(xr[k + 0], wreg[k + 0], acc0);
            acc1 = fmaf(xr[k + 1], wreg[k + 1], acc1);
            acc2 = fmaf(xr[k + 2], wreg[k + 2], acc2);
            acc3 = fmaf(xr[k + 3], wreg[k + 3], acc3);
        }
        float acc = (acc0 + acc1) + (acc2 + acc3);
        m[(size_t)iu * 64 + lane] = acc;
        float t1 = acc * a1;
        float t2 = acc * a2;
#pragma unroll
        for (int off = 1; off < 64; off <<= 1) {
            t1 += __shfl_xor(t1, off);
            t2 += __shfl_xor(t2, off);
        }
        if (lane == 0) { p[iu] = t1; q[iu] = t2; }
    }
}

// ---------------- CSR build ----------------
__global__ __launch_bounds__(256) void hist1(const int* __restrict__ seg,
                                             int* __restrict__ counts, int base, int E)
{
    int k = blockIdx.x * blockDim.x + threadIdx.x;
    if (k < E) atomicAdd(&counts[base + seg[k]], 1);
}

__global__ __launch_bounds__(256) void hist2(const int* __restrict__ a, const int* __restrict__ b,
                                             int* __restrict__ counts, int baseA, int baseB, int E)
{
    int k = blockIdx.x * blockDim.x + threadIdx.x;
    if (k < E) {
        atomicAdd(&counts[baseA + a[k]], 1);
        atomicAdd(&counts[baseB + b[k]], 1);
    }
}

__global__ __launch_bounds__(SCAN_BLK) void scan_partial(const int* __restrict__ in,
                                                         int* __restrict__ out,
                                                         int* __restrict__ bsums, int n)
{
    __shared__ int lds[SCAN_BLK];
    int base = blockIdx.x * SCAN_ELEMS + threadIdx.x * 8;
    int v[8]; int s = 0;
#pragma unroll
    for (int k = 0; k < 8; ++k) { int x = (base + k < n) ? in[base + k] : 0; v[k] = s; s += x; }
    lds[threadIdx.x] = s;
    __syncthreads();
    int t = s;
    for (int off = 1; off < SCAN_BLK; off <<= 1) {
        int y = (threadIdx.x >= off) ? lds[threadIdx.x - off] : 0;
        __syncthreads();
        t += y;
        lds[threadIdx.x] = t;
        __syncthreads();
    }
    int excl = t - s;
    if (threadIdx.x == SCAN_BLK - 1) bsums[blockIdx.x] = t;
#pragma unroll
    for (int k = 0; k < 8; ++k) if (base + k < n) out[base + k] = excl + v[k];
}

__global__ __launch_bounds__(1024) void scan_top(int* __restrict__ bsums, int nb)
{
    __shared__ int lds[1024];
    int x = (threadIdx.x < nb) ? bsums[threadIdx.x] : 0;
    lds[threadIdx.x] = x;
    __syncthreads();
    int t = x;
    for (int off = 1; off < 1024; off <<= 1) {
        int y = (threadIdx.x >= off) ? lds[threadIdx.x - off] : 0;
        __syncthreads();
        t += y;
        lds[threadIdx.x] = t;
        __syncthreads();
    }
    if (threadIdx.x < nb) bsums[threadIdx.x] = t - x;
}

__global__ __launch_bounds__(256) void scan_addback(int* __restrict__ out,
                                                    const int* __restrict__ bsums, int n)
{
    int i = blockIdx.x * blockDim.x + threadIdx.x;
    if (i < n) out[i] += bsums[i / SCAN_ELEMS];
}

// reverse-fill buckets using counts as countdown cursors
__global__ __launch_bounds__(256) void place1(const int* __restrict__ seg, const int* __restrict__ other,
                                              const int* __restrict__ rs, int* __restrict__ counts,
                                              int* __restrict__ colsAll, int base, int E)
{
    int k = blockIdx.x * blockDim.x + threadIdx.x;
    if (k >= E) return;
    int s = base + seg[k];
    int off = atomicSub(&counts[s], 1) - 1;
    colsAll[rs[s] + off] = other[k];
}

__global__ __launch_bounds__(256) void place2(const int* __restrict__ a, const int* __restrict__ b,
                                              const int* __restrict__ rs, int* __restrict__ counts,
                                              int* __restrict__ colsAll, int baseA, int baseB, int E)
{
    int k = blockIdx.x * blockDim.x + threadIdx.x;
    if (k >= E) return;
    int av = a[k], bv = b[k];
    int sa = baseA + av;
    int offa = atomicSub(&counts[sa], 1) - 1;
    colsAll[rs[sa] + offa] = bv;
    int sb = baseB + bv;
    int offb = atomicSub(&counts[sb], 1) - 1;
    colsAll[rs[sb] + offb] = av;
}

// ---------------- segment aggregation (16 lanes = quarter-wave per row) ----------------
// out[row] += sum_e exp(lrelu(uni[row]+gat[col_e])) * feat[col_e]  / sum_e exp(...)
// Each lane owns a float4 of the 64-wide feature vector; no cross-lane shuffles needed
// (weights/denominator are replicated across the 16 lanes of a quarter).
__global__ __launch_bounds__(256) void seg_agg(
    const int* __restrict__ rs, const int* __restrict__ cols,
    const float* __restrict__ uni, const float* __restrict__ gat,
    const float* __restrict__ feat, float* __restrict__ out, int n)
{
    const int sub = threadIdx.x & 15;                       // float4 index within row
    int row = (int)((blockIdx.x * blockDim.x + threadIdx.x) >> 4);
    if (row >= n) return;
    int e0 = rs[row], e1 = rs[row + 1];
    if (e0 >= e1) return;             // empty row: leave zeros (avoid 0/0)
    const float pu = uni[row];
    const float4* __restrict__ feat4 = (const float4*)feat;
    float4 acc = make_float4(0.f, 0.f, 0.f, 0.f);
    float ssum = 0.f;
    int e = e0;
    for (; e + 1 < e1; e += 2) {
        int c0 = cols[e], c1 = cols[e + 1];
        float g0 = gat[c0], g1 = gat[c1];
        float4 f0 = feat4[(size_t)c0 * 16 + sub];
        float4 f1 = feat4[(size_t)c1 * 16 + sub];
        float t0 = pu + g0; t0 = (t0 > 0.f) ? t0 : LRELU_SLOPE * t0;
        float t1 = pu + g1; t1 = (t1 > 0.f) ? t1 : LRELU_SLOPE * t1;
        float w0 = __expf(t0);
        float w1 = __expf(t1);
        ssum += w0 + w1;
        acc.x = fmaf(w0, f0.x, acc.x); acc.y = fmaf(w0, f0.y, acc.y);
        acc.z = fmaf(w0, f0.z, acc.z); acc.w = fmaf(w0, f0.w, acc.w);
        acc.x = fmaf(w1, f1.x, acc.x); acc.y = fmaf(w1, f1.y, acc.y);
        acc.z = fmaf(w1, f1.z, acc.z); acc.w = fmaf(w1, f1.w, acc.w);
    }
    if (e < e1) {
        int c0 = cols[e];
        float g0 = gat[c0];
        float4 f0 = feat4[(size_t)c0 * 16 + sub];
        float t0 = pu + g0; t0 = (t0 > 0.f) ? t0 : LRELU_SLOPE * t0;
        float w0 = __expf(t0);
        ssum += w0;
        acc.x = fmaf(w0, f0.x, acc.x); acc.y = fmaf(w0, f0.y, acc.y);
        acc.z = fmaf(w0, f0.z, acc.z); acc.w = fmaf(w0, f0.w, acc.w);
    }
    float inv = __frcp_rn(ssum);
    float4* __restrict__ out4 = (float4*)out;
    float4 o = out4[(size_t)row * 16 + sub];
    o.x = fmaf(acc.x, inv, o.x); o.y = fmaf(acc.y, inv, o.y);
    o.z = fmaf(acc.z, inv, o.z); o.w = fmaf(acc.w, inv, o.w);
    out4[(size_t)row * 16 + sub] = o;
}

extern "C" void kernel_launch(void* const* d_in, const int* in_sizes, int n_in,
                              void* d_out, int out_size, void* d_ws, size_t ws_size,
                              hipStream_t stream)
{
    const float* x0 = (const float*)d_in[0];
    const float* x1 = (const float*)d_in[1];
    const float* x2 = (const float*)d_in[2];
    const float* x3 = (const float*)d_in[3];
    const float* hbsW = (const float*)d_in[4];
    const float* hbsA = (const float*)d_in[5];
    const float* hWs  = (const float*)d_in[6];
    const float* hWt  = (const float*)d_in[7];
    const float* hA   = (const float*)d_in[8];
    const int* a0r = (const int*)d_in[9];  const int* a0c = (const int*)d_in[10];
    const int* a1r = (const int*)d_in[11]; const int* a1c = (const int*)d_in[12];
    const int* a2r = (const int*)d_in[13]; const int* a2c = (const int*)d_in[14];
    const int* c3r = (const int*)d_in[15]; const int* c3c = (const int*)d_in[16];
    const int* i1r = (const int*)d_in[17]; const int* i1c = (const int*)d_in[18];
    const int* i2r = (const int*)d_in[19]; const int* i2c = (const int*)d_in[20];
    const int* i3r = (const int*)d_in[21]; const int* i3c = (const int*)d_in[22];

    const int n0 = in_sizes[0] / 64, n1 = in_sizes[1] / 64;
    const int n2 = in_sizes[2] / 64, n3 = in_sizes[3] / 64;
    const int Ea0 = in_sizes[9],  Ea1 = in_sizes[11], Ea2 = in_sizes[13], Ec3 = in_sizes[15];
    const int Ei1 = in_sizes[17], Ei2 = in_sizes[19], Ei3 = in_sizes[21];

    int nm = n0; if (n1 > nm) nm = n1; if (n2 > nm) nm = n2; if (n3 > nm) nm = n3;

    // CSR bases (concatenated rows): adj0,adj1,adj2,c3, i1t(n0), i1s(n1), i2t(n1), i2s(n2), i3t(n2), i3s(n3)
    int b_adj0 = 0;
    int b_adj1 = b_adj0 + n0;
    int b_adj2 = b_adj1 + n1;
    int b_c3   = b_adj2 + n2;
    int b_i1t  = b_c3   + n3;
    int b_i1s  = b_i1t  + n0;
    int b_i2t  = b_i1s  + n1;
    int b_i2s  = b_i2t  + n1;
    int b_i3t  = b_i2s  + n2;
    int b_i3s  = b_i3t  + n2;
    int NC     = b_i3s  + n3 + 1;   // +1 sentinel
    long long eTot = (long long)Ea0 + Ea1 + Ea2 + Ec3 + 2LL * (Ei1 + Ei2 + Ei3);

    float* w = (float*)d_ws;
    size_t off = 0;
    auto allocf = [&](size_t nel) { float* r = w + off; off += nel; return r; };
    float* featA = allocf((size_t)nm * 64);
    float* featB = allocf((size_t)nm * 64);
    float* xl10  = allocf((size_t)n0 * 64);   // layer-1 activations (contiguous, one memset)
    float* xl11  = allocf((size_t)n1 * 64);
    float* xl12  = allocf((size_t)n2 * 64);
    float* xl13  = allocf((size_t)n3 * 64);
    float* pA = allocf(nm); float* qA = allocf(nm);
    float* pB = allocf(nm); float* qB = allocf(nm);
    int* counts  = (int*)allocf((size_t)NC);
    int* rs      = (int*)allocf((size_t)NC);
    int* bsums   = (int*)allocf(1024);
    int* colsAll = (int*)allocf((size_t)eTot);

    if (off * sizeof(float) > ws_size) {
        hipMemsetAsync(d_out, 0, (size_t)out_size * sizeof(float), stream);
        return;
    }

    float* out  = (float*)d_out;
    float* out0 = out;
    float* out1 = out0 + (size_t)n0 * 64;
    float* out2 = out1 + (size_t)n1 * 64;
    float* out3 = out2 + (size_t)n2 * 64;

    hipMemsetAsync(xl10, 0, (size_t)(n0 + n1 + n2 + n3) * 64 * sizeof(float), stream);
    hipMemsetAsync(counts, 0, (size_t)NC * sizeof(int), stream);
    hipMemsetAsync(d_out, 0, (size_t)out_size * sizeof(float), stream);

    auto blks = [](int n, int per) { return dim3((unsigned)((n + per - 1) / per)); };

    // ---- CSR build ----
    hist1<<<blks(Ea0, 256), 256, 0, stream>>>(a0r, counts, b_adj0, Ea0);
    hist1<<<blks(Ea1, 256), 256, 0, stream>>>(a1r, counts, b_adj1, Ea1);
    hist1<<<blks(Ea2, 256), 256, 0, stream>>>(a2r, counts, b_adj2, Ea2);
    hist1<<<blks(Ec3, 256), 256, 0, stream>>>(c3r, counts, b_c3,  Ec3);
    hist2<<<blks(Ei1, 256), 256, 0, stream>>>(i1r, i1c, counts, b_i1t, b_i1s, Ei1);
    hist2<<<blks(Ei2, 256), 256, 0, stream>>>(i2r, i2c, counts, b_i2t, b_i2s, Ei2);
    hist2<<<blks(Ei3, 256), 256, 0, stream>>>(i3r, i3c, counts, b_i3t, b_i3s, Ei3);

    int nb = (NC + SCAN_ELEMS - 1) / SCAN_ELEMS;
    scan_partial<<<dim3((unsigned)nb), SCAN_BLK, 0, stream>>>(counts, rs, bsums, NC);
    scan_top<<<dim3(1), 1024, 0, stream>>>(bsums, nb);
    scan_addback<<<blks(NC, 256), 256, 0, stream>>>(rs, bsums, NC);

    place1<<<blks(Ea0, 256), 256, 0, stream>>>(a0r, a0c, rs, counts, colsAll, b_adj0, Ea0);
    place1<<<blks(Ea1, 256), 256, 0, stream>>>(a1r, a1c, rs, counts, colsAll, b_adj1, Ea1);
    place1<<<blks(Ea2, 256), 256, 0, stream>>>(a2r, a2c, rs, counts, colsAll, b_adj2, Ea2);
    place1<<<blks(Ec3, 256), 256, 0, stream>>>(c3r, c3c, rs, counts, colsAll, b_c3,  Ec3);
    place2<<<blks(Ei1, 256), 256, 0, stream>>>(i1r, i1c, rs, counts, colsAll, b_i1t, b_i1s, Ei1);
    place2<<<blks(Ei2, 256), 256, 0, stream>>>(i2r, i2c, rs, counts, colsAll, b_i2t, b_i2s, Ei2);
    place2<<<blks(Ei3, 256), 256, 0, stream>>>(i3r, i3c, rs, counts, colsAll, b_i3t, b_i3s, Ei3);

    auto gemm = [&](const float* xx, const float* WW, const float* aa,
                    float* mm, float* pp, float* qq, int n) {
        gemm_pq_kernel<<<blks(n, 4), 256, 0, stream>>>(xx, WW, aa, mm, pp, qq, n);
    };
    auto agg = [&](int base, const float* uni, const float* gat,
                   const float* feat, float* outp, int n) {
        seg_agg<<<blks(n, 16), 256, 0, stream>>>(rs + base, colsAll, uni, gat, feat, outp, n);
    };

    // ---------------- Layer 1 ----------------
    gemm(x0, hbsW + 0 * 4096, hbsA + 0 * 128, featA, pA, qA, n0);
    agg(b_adj0, pA, qA, featA, xl10, n0);                          // x00

    gemm(x1, hWs + 0 * 4096, hA + 0 * 128, featA, pA, qA, n1);     // sm
    gemm(x0, hWt + 0 * 4096, hA + 0 * 128, featB, pB, qB, n0);     // tm
    agg(b_i1t, qB, pA, featA, xl10, n0);   // x10: e = lrelu(sm_j·a1 + tm_i·a2)
    agg(b_i1s, qA, pB, featB, xl11, n1);   // x01: f = lrelu(tm_i·a1 + sm_j·a2)

    gemm(x2, hWs + 1 * 4096, hA + 1 * 128, featA, pA, qA, n2);
    gemm(x1, hWt + 1 * 4096, hA + 1 * 128, featB, pB, qB, n1);
    agg(b_i2t, qB, pA, featA, xl11, n1);   // x21
    agg(b_i2s, qA, pB, featB, xl12, n2);   // x12

    gemm(x3, hWs + 2 * 4096, hA + 2 * 128, featA, pA, qA, n3);
    gemm(x2, hWt + 2 * 4096, hA + 2 * 128, featB, pB, qB, n2);
    agg(b_i3t, qB, pA, featA, xl12, n2);   // x32
    agg(b_i3s, qA, pB, featB, xl13, n3);   // x23

    // ---------------- Layer 2 ----------------
    gemm(xl10, hbsW + 1 * 4096, hbsA + 1 * 128, featA, pA, qA, n0);
    agg(b_adj0, pA, qA, featA, out0, n0);                          // y00

    gemm(xl11, hbsW + 2 * 4096, hbsA + 2 * 128, featA, pA, qA, n1);
    agg(b_adj1, pA, qA, featA, out1, n1);                          // y11

    gemm(xl12, hbsW + 3 * 4096, hbsA + 3 * 128, featA, pA, qA, n2);
    agg(b_adj2, pA, qA, featA, out2, n2);                          // y22

    gemm(xl13, hbsW + 4 * 4096, hbsA + 4 * 128, featA, pA, qA, n3);
    agg(b_c3, pA, qA, featA, out3, n3);                            // y33

    // y01 = msg_s of hbns(xl11, xl10, inc1) [Ws3, Wt3, a3]
    gemm(xl11, hWs + 3 * 4096, hA + 3 * 128, featA, pA, qA, n1);
    gemm(xl10, hWt + 3 * 4096, hA + 3 * 128, featB, pB, qB, n0);
    agg(b_i1s, qA, pB, featB, out1, n1);

    // y12 = msg_s of hbns(xl12, xl11, inc2) [Ws4, Wt4, a4]
    gemm(xl12, hWs + 4 * 4096, hA + 4 * 128, featA, pA, qA, n2);
    gemm(xl11, hWt + 4 * 4096, hA + 4 * 128, featB, pB, qB, n1);
    agg(b_i2s, qA, pB, featB, out2, n2);

    // y23 = msg_s of hbns(xl13, xl12, inc3) [Ws5, Wt5, a5]
    gemm(xl13, hWs + 5 * 4096, hA + 5 * 128, featA, pA, qA, n3);
    gemm(xl12, hWt + 5 * 4096, hA + 5 * 128, featB, pB, qB, n2);
    agg(b_i3s, qA, pB, featB, out3, n3);
}